// Round 1
// baseline (536.654 us; speedup 1.0000x reference)
//
#include <hip/hip_runtime.h>
#include <hip/hip_bf16.h>
#include <cstdint>

#define ENC_DEPTH 8
#define RAYS_PER_BLOCK 64
#define THREADS 512

typedef __attribute__((ext_vector_type(8))) short bf16x8;
typedef __attribute__((ext_vector_type(4))) float f32x4;

__device__ __forceinline__ unsigned short f2bf(float x) {
    union { float f; unsigned u; } v; v.f = x;
    unsigned r = v.u + 0x7fffu + ((v.u >> 16) & 1u);
    return (unsigned short)(r >> 16);
}
__device__ __forceinline__ float bf2f(unsigned short h) {
    union { unsigned u; float f; } v; v.u = ((unsigned)h) << 16;
    return v.f;
}
__device__ __forceinline__ float clamp01(float x) {
    return fminf(fmaxf(x, 0.0f), 1.0f);
}

// LDS strides (in elements), chosen for bank-conflict freedom + 16B alignment:
//  corners_s: per-ray stride 136 bf16 (272 B) -> A2 b128 reads conflict-free
//  feat_s / w1t_s: per-row stride 144 bf16 (288 B) -> 2-way max (free)
//  h1_s: stride 65 fp32
__global__ __launch_bounds__(THREADS, 4) void nbvh_kernel(
    const float* __restrict__ orig, const float* __restrict__ endp,
    const int* __restrict__ hist, const float* __restrict__ nodes_min,
    const float* __restrict__ nodes_extent, const float* __restrict__ emb,
    const float* __restrict__ W1, const float* __restrict__ W2,
    const float* __restrict__ W3, float* __restrict__ out)
{
    __shared__ int hist_s[RAYS_PER_BLOCK * ENC_DEPTH];
    __shared__ float oe_s[RAYS_PER_BLOCK * 6];
    __shared__ __align__(16) unsigned short corners_s[RAYS_PER_BLOCK * 136];
    __shared__ __align__(16) unsigned short feat_s[RAYS_PER_BLOCK * 144];
    __shared__ __align__(16) unsigned short w1t_s[64 * 144];
    __shared__ float h1_s[RAYS_PER_BLOCK * 65];

    const int t = threadIdx.x;
    const int r0 = blockIdx.x * RAYS_PER_BLOCK;
    const int wave = t >> 6;
    const int lane = t & 63;

    // ---- prologue: stage history + orig/end for 64 rays ----
    hist_s[t] = hist[r0 * ENC_DEPTH + t];
    if (t < RAYS_PER_BLOCK * 3) {
        int ray = t / 3, c = t - ray * 3;
        oe_s[ray * 6 + c]     = orig[(r0 + ray) * 3 + c];
        oe_s[ray * 6 + 3 + c] = endp[(r0 + ray) * 3 + c];
    }

    f32x4 acc0 = {0.f, 0.f, 0.f, 0.f};
    f32x4 acc1 = {0.f, 0.f, 0.f, 0.f};
    const int m0 = (wave >> 1) * 16;   // ray-row base of this wave's C stripe
    const int n0 = (wave & 1) * 32;    // col base (two 16-wide tiles)

    __syncthreads();

    for (int d = 0; d < ENC_DEPTH; ++d) {
        // ---- stage corners (transpose to [f*8+k], bf16) ----
        {
            int ray = t >> 3, k = t & 7;
            int node = hist_s[(ray << 3) + d];
            const float4* ep = (const float4*)(emb + ((size_t)node << 7) + (k << 4));
            float4 e0 = ep[0], e1 = ep[1], e2 = ep[2], e3 = ep[3];
            float e[16];
            e[0]=e0.x; e[1]=e0.y; e[2]=e0.z; e[3]=e0.w;
            e[4]=e1.x; e[5]=e1.y; e[6]=e1.z; e[7]=e1.w;
            e[8]=e2.x; e[9]=e2.y; e[10]=e2.z; e[11]=e2.w;
            e[12]=e3.x; e[13]=e3.y; e[14]=e3.z; e[15]=e3.w;
            unsigned short* cb = corners_s + ray * 136 + k;
            #pragma unroll
            for (int f = 0; f < 16; ++f) cb[f << 3] = f2bf(e[f]);
        }
        // ---- stage W1 chunk, transposed to N-major bf16 ----
        {
            int rl = t >> 2, cg = (t & 3) << 4;   // rl = k-row in chunk, cg = col group
            const float4* wp = (const float4*)(W1 + (size_t)(d * 128 + rl) * 64 + cg);
            float4 a0v = wp[0], a1v = wp[1], a2v = wp[2], a3v = wp[3];
            float a[16];
            a[0]=a0v.x; a[1]=a0v.y; a[2]=a0v.z; a[3]=a0v.w;
            a[4]=a1v.x; a[5]=a1v.y; a[6]=a1v.z; a[7]=a1v.w;
            a[8]=a2v.x; a[9]=a2v.y; a[10]=a2v.z; a[11]=a2v.w;
            a[12]=a3v.x; a[13]=a3v.y; a[14]=a3v.z; a[15]=a3v.w;
            unsigned short* wb = w1t_s + (size_t)cg * 144 + rl;
            #pragma unroll
            for (int i = 0; i < 16; ++i) wb[i * 144] = f2bf(a[i]);
        }
        __syncthreads();

        // ---- A2: trilinear weights + feat chunk ----
        {
            int ray = t >> 3, p = t & 7;
            int node = hist_s[(ray << 3) + d];
            float nm0 = nodes_min[node * 3 + 0];
            float nm1 = nodes_min[node * 3 + 1];
            float nm2 = nodes_min[node * 3 + 2];
            float ex0 = nodes_extent[node * 3 + 0];
            float ex1 = nodes_extent[node * 3 + 1];
            float ex2 = nodes_extent[node * 3 + 2];
            const float* oe = oe_s + ray * 6;
            float po0 = clamp01((oe[0] - nm0) / ex0);
            float po1 = clamp01((oe[1] - nm1) / ex1);
            float po2 = clamp01((oe[2] - nm2) / ex2);
            float pe0 = clamp01((oe[3] - nm0) / ex0);
            float pe1 = clamp01((oe[4] - nm1) / ex1);
            float pe2 = clamp01((oe[5] - nm2) / ex2);
            float tt = (float)p * (1.0f / 7.0f);
            float x = po0 + (pe0 - po0) * tt;
            float y = po1 + (pe1 - po1) * tt;
            float z = po2 + (pe2 - po2) * tt;
            float ox = 1.f - x, oy = 1.f - y, oz = 1.f - z;
            float w[8];
            w[0] = ox * oy * oz;  w[1] = x * oy * oz;
            w[2] = ox * y * oz;   w[3] = ox * oy * z;
            w[4] = x * oy * z;    w[5] = ox * y * z;
            w[6] = x * y * oz;    w[7] = x * y * z;
            const unsigned short* cbase = corners_s + ray * 136;
            unsigned short* fb = feat_s + ray * 144 + (p << 4);
            #pragma unroll
            for (int f = 0; f < 16; ++f) {
                bf16x8 cv = *(const bf16x8*)(cbase + (f << 3));
                float acc = 0.f;
                #pragma unroll
                for (int k = 0; k < 8; ++k)
                    acc = fmaf(w[k], bf2f((unsigned short)cv[k]), acc);
                fb[f] = f2bf(acc);
            }
        }
        __syncthreads();

        // ---- MFMA: accumulate this K=128 chunk ----
        {
            int q = lane >> 4, c = lane & 15;
            #pragma unroll
            for (int kk = 0; kk < 4; ++kk) {
                int koff = kk * 32 + q * 8;
                bf16x8 af = *(const bf16x8*)(feat_s + (m0 + c) * 144 + koff);
                bf16x8 b0 = *(const bf16x8*)(w1t_s + (n0 + c) * 144 + koff);
                bf16x8 b1 = *(const bf16x8*)(w1t_s + (n0 + 16 + c) * 144 + koff);
                acc0 = __builtin_amdgcn_mfma_f32_16x16x32_bf16(af, b0, acc0, 0, 0, 0);
                acc1 = __builtin_amdgcn_mfma_f32_16x16x32_bf16(af, b1, acc1, 0, 0, 0);
            }
        }
        __syncthreads();
    }

    // ---- h1 = relu(GEMM1) -> LDS (C layout: col=lane&15, row=(lane>>4)*4+r) ----
    {
        int colb = lane & 15, rq = (lane >> 4) << 2;
        #pragma unroll
        for (int r = 0; r < 4; ++r) {
            h1_s[(m0 + rq + r) * 65 + n0 + colb]      = fmaxf(acc0[r], 0.f);
            h1_s[(m0 + rq + r) * 65 + n0 + 16 + colb] = fmaxf(acc1[r], 0.f);
        }
    }
    __syncthreads();

    // ---- GEMM2: h2 = relu(h1 @ W2), fp32 VALU; h2 aliases corners_s ----
    float* h2_s = (float*)corners_s;   // stride 66 fp32, 64*66*4 = 16896 B <= 17408 B
    {
        int ray = t >> 3, jg = (t & 7) << 3;
        float s[8];
        #pragma unroll
        for (int j = 0; j < 8; ++j) s[j] = 0.f;
        const float* hrow = h1_s + ray * 65;
        #pragma unroll 8
        for (int i = 0; i < 64; ++i) {
            float hv = hrow[i];
            const float4* wr = (const float4*)(W2 + (i << 6) + jg);
            float4 wa = wr[0], wb = wr[1];
            s[0] = fmaf(hv, wa.x, s[0]); s[1] = fmaf(hv, wa.y, s[1]);
            s[2] = fmaf(hv, wa.z, s[2]); s[3] = fmaf(hv, wa.w, s[3]);
            s[4] = fmaf(hv, wb.x, s[4]); s[5] = fmaf(hv, wb.y, s[5]);
            s[6] = fmaf(hv, wb.z, s[6]); s[7] = fmaf(hv, wb.w, s[7]);
        }
        float* hb = h2_s + ray * 66 + jg;
        #pragma unroll
        for (int j = 0; j < 8; ++j) hb[j] = fmaxf(s[j], 0.f);
    }
    __syncthreads();

    // ---- GEMM3 + output ----
    if (t < 128) {
        int ray = t >> 1, c = t & 1;
        const float* hrow = h2_s + ray * 66;
        float a = 0.f;
        #pragma unroll 16
        for (int i = 0; i < 64; ++i) a = fmaf(hrow[i], W3[i * 2 + c], a);
        if (c) {
            const float* oe = oe_s + ray * 6;
            float dx = oe[3] - oe[0], dy = oe[4] - oe[1], dz = oe[5] - oe[2];
            a *= sqrtf(dx * dx + dy * dy + dz * dz);
        }
        out[((r0 + ray) << 1) + c] = a;
    }
}

extern "C" void kernel_launch(void* const* d_in, const int* in_sizes, int n_in,
                              void* d_out, int out_size, void* d_ws, size_t ws_size,
                              hipStream_t stream) {
    const float* orig = (const float*)d_in[0];
    const float* endp = (const float*)d_in[1];
    const int*   hist = (const int*)d_in[2];
    const float* nmin = (const float*)d_in[3];
    const float* next = (const float*)d_in[4];
    const float* emb  = (const float*)d_in[5];
    const float* W1   = (const float*)d_in[6];
    const float* W2   = (const float*)d_in[7];
    const float* W3   = (const float*)d_in[8];
    float* out = (float*)d_out;
    const int n_rays = in_sizes[0] / 3;
    dim3 grid(n_rays / RAYS_PER_BLOCK);
    nbvh_kernel<<<grid, THREADS, 0, stream>>>(orig, endp, hist, nmin, next,
                                              emb, W1, W2, W3, out);
}